// Round 3
// baseline (186.276 us; speedup 1.0000x reference)
//
#include <hip/hip_runtime.h>

#define B_ 4
#define N_ 7
#define L_ 512
#define S_ 512
#define H_ 8
#define E_ 64
#define D_ 64

constexpr int QT = 128;       // Q rows per block (8 waves x 16 rows)
constexpr int ST = 128;       // S rows per LDS tile
constexpr int NT = S_ / ST;   // 4 S-tiles
constexpr int KP = 72;        // K LDS row pitch (f16) -> 144B
constexpr int VP = 132;       // Vt LDS row pitch; columns XOR-swizzled by (d&28)

typedef _Float16 f16x8 __attribute__((ext_vector_type(8)));
typedef _Float16 f16x4 __attribute__((ext_vector_type(4)));
typedef float    f32x4 __attribute__((ext_vector_type(4)));

// 512 threads; double-buffered LDS (70.7 KB) -> 2 blocks/CU
__global__ __launch_bounds__(512, 4)
void attn_fwd(const float* __restrict__ Q, const float* __restrict__ K,
              const float* __restrict__ V, float* __restrict__ O)
{
    __shared__ _Float16 Ks[2][ST * KP];   // K tile, row-major [s][e]
    __shared__ _Float16 Vs[2][D_ * VP];   // V tile transposed [d][s^swz(d)]

    const int bnh   = blockIdx.x;              // 0..223 (siblings 224 apart -> same XCD)
    const int h     = bnh & (H_ - 1);
    const int bn    = bnh >> 3;
    const int qbase = blockIdx.y * QT;

    const int tid  = threadIdx.x;
    const int wid  = tid >> 6;                 // wave id 0..7, owns Q rows [wid*16, +16)
    const int lane = tid & 63;
    const int quad = lane >> 4;
    const int m16  = lane & 15;

    const float* Qp = Q + ((size_t)bn * L_ * H_ + h) * E_;
    const float* Kp = K + ((size_t)bn * S_ * H_ + h) * E_;
    const float* Vp = V + ((size_t)bn * S_ * H_ + h) * D_;
    float*       Op = O + ((size_t)bn * L_ * H_ + h) * D_;

    // staging decomposition shared by K and V (E_ == D_ == 64)
    const int sr = tid >> 4;            // row step base (r = j*32 + sr)
    const int sc = (tid & 15) * 4;      // col 0..60 step 4
    const int vswz = sc & 28;           // V column swizzle (uniform over the 4 elems)

    auto load_tile = [&](int sb, float4 (&kreg)[4], float4 (&vreg)[4]) {
        #pragma unroll
        for (int j = 0; j < 4; ++j) {
            int r = j * 32 + sr;
            kreg[j] = *(const float4*)(Kp + (size_t)(sb + r) * (H_*E_) + sc);
            vreg[j] = *(const float4*)(Vp + (size_t)(sb + r) * (H_*D_) + sc);
        }
    };
    auto store_tile = [&](int buf, const float4 (&kreg)[4], const float4 (&vreg)[4]) {
        #pragma unroll
        for (int j = 0; j < 4; ++j) {
            int r = j * 32 + sr;
            f16x4 w;
            w[0]=(_Float16)kreg[j].x; w[1]=(_Float16)kreg[j].y;
            w[2]=(_Float16)kreg[j].z; w[3]=(_Float16)kreg[j].w;
            *(f16x4*)&Ks[buf][r*KP + sc] = w;
            int rs = r ^ vswz;
            Vs[buf][(sc+0)*VP + rs] = (_Float16)vreg[j].x;
            Vs[buf][(sc+1)*VP + rs] = (_Float16)vreg[j].y;
            Vs[buf][(sc+2)*VP + rs] = (_Float16)vreg[j].z;
            Vs[buf][(sc+3)*VP + rs] = (_Float16)vreg[j].w;
        }
    };

    // ---- Q fragments (B-operand of St = K*Q^T), scale 1/sqrt(E)*log2(e) folded ----
    const float qsc = 0.125f * 1.4426950408889634f;
    f16x8 qf[2];
    #pragma unroll
    for (int kt = 0; kt < 2; ++kt) {
        const float* p = Qp + (size_t)(qbase + wid*16 + m16) * (H_*E_) + kt*32 + quad*8;
        float4 a = *(const float4*)p;
        float4 b = *(const float4*)(p + 4);
        f16x8 f;
        f[0]=(_Float16)(a.x*qsc); f[1]=(_Float16)(a.y*qsc);
        f[2]=(_Float16)(a.z*qsc); f[3]=(_Float16)(a.w*qsc);
        f[4]=(_Float16)(b.x*qsc); f[5]=(_Float16)(b.y*qsc);
        f[6]=(_Float16)(b.z*qsc); f[7]=(_Float16)(b.w*qsc);
        qf[kt] = f;
    }

    const f32x4 fzero = {0.f, 0.f, 0.f, 0.f};
    f32x4 of[4];
    #pragma unroll
    for (int dt = 0; dt < 4; ++dt) of[dt] = fzero;

    float m_run = -1e30f;
    float l_run = 0.f;

    // ---- prologue: tile 0 -> regs -> LDS buf0 ----
    float4 kreg[4], vreg[4];
    load_tile(0, kreg, vreg);
    store_tile(0, kreg, vreg);
    __syncthreads();

    #pragma unroll
    for (int it = 0; it < NT; ++it) {
        const int cur = it & 1;

        // issue next tile's global loads (results unused until after compute ->
        // compiler defers the vmcnt wait; latency overlaps MFMA+softmax)
        if (it + 1 < NT) load_tile((it + 1) * ST, kreg, vreg);

        // ---- St = K*Q^T : C value = score(l = m16, s = st*16 + quad*4 + reg) ----
        f32x4 acc[8];
        #pragma unroll
        for (int st = 0; st < 8; ++st) acc[st] = fzero;
        #pragma unroll
        for (int st = 0; st < 8; ++st) {
            #pragma unroll
            for (int kt = 0; kt < 2; ++kt) {
                f16x8 kf = *(const f16x8*)&Ks[cur][(st*16 + m16)*KP + kt*32 + quad*8];
                acc[st] = __builtin_amdgcn_mfma_f32_16x16x32_f16(kf, qf[kt], acc[st], 0,0,0);
            }
        }

        // ---- online softmax, per Q-row (= St column, keyed by m16) ----
        {
            float mt = -1e30f;
            #pragma unroll
            for (int st = 0; st < 8; ++st)
                mt = fmaxf(mt, fmaxf(fmaxf(acc[st][0], acc[st][1]),
                                     fmaxf(acc[st][2], acc[st][3])));
            mt = fmaxf(mt, __shfl_xor(mt, 16));
            mt = fmaxf(mt, __shfl_xor(mt, 32));
            float mnew  = fmaxf(m_run, mt);
            float alpha = exp2f(m_run - mnew);
            float rsum = 0.f;
            #pragma unroll
            for (int st = 0; st < 8; ++st)
                #pragma unroll
                for (int r = 0; r < 4; ++r) {
                    float p = exp2f(acc[st][r] - mnew);
                    acc[st][r] = p;
                    rsum += p;
                }
            rsum += __shfl_xor(rsum, 16);
            rsum += __shfl_xor(rsum, 32);
            l_run = l_run * alpha + rsum;
            m_run = mnew;
            #pragma unroll
            for (int r = 0; r < 4; ++r) {
                float aO = __shfl(alpha, quad*4 + r);
                #pragma unroll
                for (int dt = 0; dt < 4; ++dt) of[dt][r] *= aO;
            }
        }

        // ---- O += P*V : P (St C-layout) is already 16x16x16 A-operand layout ----
        #pragma unroll
        for (int st = 0; st < 8; ++st) {
            f16x4 pf;
            pf[0]=(_Float16)acc[st][0]; pf[1]=(_Float16)acc[st][1];
            pf[2]=(_Float16)acc[st][2]; pf[3]=(_Float16)acc[st][3];
            #pragma unroll
            for (int dt = 0; dt < 4; ++dt) {
                int d  = dt*16 + m16;
                f16x4 vf = *(const f16x4*)&Vs[cur][d*VP + ((st*16 + quad*4) ^ (d & 28))];
                of[dt] = __builtin_amdgcn_mfma_f32_16x16x16f16(pf, vf, of[dt], 0,0,0);
            }
        }

        // ---- stage prefetched tile into the other buffer; WAR on buf (cur^1)
        //      is protected by the barrier at the END of iteration it-1 ----
        if (it + 1 < NT) {
            store_tile(cur ^ 1, kreg, vreg);
            __syncthreads();
        }
    }

    // ---- epilogue: normalize by l_run and store (16-lane 64B contiguous chunks) ----
    #pragma unroll
    for (int r = 0; r < 4; ++r) {
        float inv = 1.0f / __shfl(l_run, quad*4 + r);
        float* op = Op + (size_t)(qbase + wid*16 + quad*4 + r)*(H_*D_) + m16;
        #pragma unroll
        for (int dt = 0; dt < 4; ++dt)
            op[dt*16] = of[dt][r] * inv;
    }
}

extern "C" void kernel_launch(void* const* d_in, const int* in_sizes, int n_in,
                              void* d_out, int out_size, void* d_ws, size_t ws_size,
                              hipStream_t stream)
{
    const float* Q = (const float*)d_in[0];
    const float* K = (const float*)d_in[1];
    const float* V = (const float*)d_in[2];
    float* O = (float*)d_out;
    dim3 grid(B_ * N_ * H_, L_ / QT);   // x=bnh (fast) -> q-tile siblings same XCD
    attn_fwd<<<grid, 512, 0, stream>>>(Q, K, V, O);
}